// Round 1
// baseline (350.329 us; speedup 1.0000x reference)
//
#include <hip/hip_runtime.h>
#include <math.h>

// GraphAttnModel: N=50000, E=800000, F=256, H=4, D=64.
// Pipeline:
//   1) prep: convert feat+weights+biases to bf16 ws copies, zero CSR counters
//   2) CSR-by-dst build (count / alloc / fill-src), scan-free wave atomics
//   3) fused bf16 MFMA GEMM (128x256 tile, global_load_lds staging).
//      Swapped-operand MFMA -> lane holds 4 consecutive cols of one row.
//      q,v outputs stored FP8 e4m3 (halves the node-phase gather bytes);
//      k,skip stored bf16.
//   4) one wave per dst node: 32-lanes-per-edge, 2 edges/iter, 2x unroll
//      (4 edges in flight). No-max softmax edge attention (logits |e|<~1;
//      softmax shift-invariant) + gate + LayerNorm + PReLU, f32 output.

typedef __attribute__((ext_vector_type(8))) short short8;   // 8 bf16 = 4 VGPRs
typedef __attribute__((ext_vector_type(4))) float floatx4;  // MFMA acc
typedef __attribute__((ext_vector_type(2))) float floatx2;  // fp8 decode pair
typedef __attribute__((address_space(3))) void lds_void;
typedef __attribute__((address_space(1))) const void gbl_void;

__device__ inline unsigned short f2bf(float x) {            // RNE f32->bf16
    unsigned int u = __float_as_uint(x);
    u = (u + 0x7fffu + ((u >> 16) & 1u)) >> 16;
    return (unsigned short)u;
}
__device__ inline float bf2f(unsigned short u) {
    return __uint_as_float(((unsigned int)u) << 16);
}

// ---------------- prep: converts + CSR zero ----------------
__global__ void prep_kernel(const float* __restrict__ f, ushort* __restrict__ fb,
                            int n_elems, int total_pad,
                            const float* __restrict__ Wq, const float* __restrict__ Wk,
                            const float* __restrict__ Wv, const float* __restrict__ Wsk,
                            const float* __restrict__ bq, const float* __restrict__ bk,
                            const float* __restrict__ bv, const float* __restrict__ bsk,
                            ushort* __restrict__ Wcat, float* __restrict__ bcat,
                            int* __restrict__ counts, int* __restrict__ cursor, int n)
{
    int g = blockIdx.x * blockDim.x + threadIdx.x;
    int featQ = total_pad >> 2;               // feat quads
    if (g < featQ) {
        int i = g * 4;
        float4 v = (i < n_elems) ? *(const float4*)(f + i) : make_float4(0.f, 0.f, 0.f, 0.f);
        ushort4 u;
        u.x = f2bf(v.x); u.y = f2bf(v.y); u.z = f2bf(v.z); u.w = f2bf(v.w);
        *(ushort4*)(fb + i) = u;
        return;
    }
    int g2 = g - featQ;
    if (g2 < 65536) {                         // weights: 262144/4
        int i = g2 * 4;
        int mat = i >> 16;
        int rem = i & 65535;
        const float* W = (mat == 0) ? Wq : (mat == 1) ? Wk : (mat == 2) ? Wv : Wsk;
        float4 v = *(const float4*)(W + rem);
        ushort4 u;
        u.x = f2bf(v.x); u.y = f2bf(v.y); u.z = f2bf(v.z); u.w = f2bf(v.w);
        *(ushort4*)(Wcat + i) = u;
        return;
    }
    int g3 = g2 - 65536;
    if (g3 < 256) {                           // biases: 1024/4
        int o = g3 * 4;
        int mat = o >> 8;
        const float* b = (mat == 0) ? bq : (mat == 1) ? bk : (mat == 2) ? bv : bsk;
        *(float4*)(bcat + o) = *(const float4*)(b + (o & 255));
        return;
    }
    int g4 = g3 - 256;
    if (g4 < n) counts[g4] = 0;
    if (g4 == 0) *cursor = 0;
}

// ---------------- CSR build ----------------

__global__ void count_kernel(const int* __restrict__ dst, int* counts, int e) {
    int i = blockIdx.x * blockDim.x + threadIdx.x;
    if (i < e) atomicAdd(&counts[dst[i]], 1);
}

__global__ void alloc_kernel(const int* __restrict__ counts, int* start, int* cur,
                             int* cursor, int n) {
    int i = blockIdx.x * blockDim.x + threadIdx.x;
    int lane = threadIdx.x & 63;
    int c = (i < n) ? counts[i] : 0;
    int incl = c;
#pragma unroll
    for (int d = 1; d < 64; d <<= 1) {
        int t = __shfl_up(incl, d);
        if (lane >= d) incl += t;
    }
    int waveTot = __shfl(incl, 63);
    int base = 0;
    if (lane == 63) base = atomicAdd(cursor, waveTot);
    base = __shfl(base, 63);
    if (i < n) {
        int s = base + incl - c;
        start[i] = s;
        cur[i] = s;
    }
}

__global__ void fill_kernel(const int* __restrict__ dst, const int* __restrict__ src,
                            int* cur, int* srclist, int e) {
    int i = blockIdx.x * blockDim.x + threadIdx.x;
    if (i < e) {
        int pos = atomicAdd(&cur[dst[i]], 1);
        srclist[pos] = src[i];
    }
}

// ---------------- fused bf16 MFMA projection GEMM ----------------
// C[m][o] = sum_k featb[m][k] * Wcat[o][k] + bcat[o],  m<50048(pad), o<1024.
// Block: 512 thr = 8 waves; tile 128m x 256n; wave tile 64x64 (4x4 MFMA).
// blockIdx.x (fastest-varying) selects output matrix -> 4 concurrent blocks
// share the same featb A-tile (L2/L3 hits). Swapped-operand MFMA:
// D[n_local][m_local], m_local=lane&15 (row), n_local=(lane>>4)*4+reg
// (4 consecutive cols). q (y=0) and v (y=2) written fp8 e4m3; k,skip bf16.
__global__ __launch_bounds__(512) void mfma_gemm(
    const ushort* __restrict__ featb, const ushort* __restrict__ Wcat,
    const float* __restrict__ bcat,
    unsigned char* __restrict__ q8, ushort* __restrict__ kb,
    unsigned char* __restrict__ v8, ushort* __restrict__ sb, int n)
{
    __shared__ ushort At[128 * 32];  // 8 KB
    __shared__ ushort Bt[256 * 32];  // 16 KB
    int tid = threadIdx.x;
    int lane = tid & 63;
    int wv = tid >> 6;               // 0..7
    int ysel = blockIdx.x;           // 0..3: q,k,v,skip
    int mBase = blockIdx.y * 128;
    int nBlk = ysel * 256;
    int mQuad = (wv & 1) * 64;
    int nQuad = (wv >> 1) * 64;

    floatx4 zero = {0.f, 0.f, 0.f, 0.f};
    floatx4 acc[4][4];               // [m-tile][n-tile]
#pragma unroll
    for (int i = 0; i < 4; ++i)
#pragma unroll
        for (int j = 0; j < 4; ++j) acc[i][j] = zero;

    int rsel = lane & 15;
    int ksel = (lane >> 4) * 8;
    int lrow = lane >> 2;            // 0..15
    int lcol = (lane & 3) * 8;       // ushort offset 0,8,16,24

    for (int k0 = 0; k0 < 256; k0 += 32) {
        {
            int row = 16 * wv + lrow;
            const ushort* gp = featb + (size_t)(mBase + row) * 256 + k0 + lcol;
            __builtin_amdgcn_global_load_lds((gbl_void*)gp, (lds_void*)&At[16 * wv * 32], 16, 0, 0);
        }
#pragma unroll
        for (int r = 0; r < 2; ++r) {
            int row = 32 * wv + 16 * r + lrow;
            const ushort* gp = Wcat + (size_t)(nBlk + row) * 256 + k0 + lcol;
            __builtin_amdgcn_global_load_lds((gbl_void*)gp, (lds_void*)&Bt[(32 * wv + 16 * r) * 32], 16, 0, 0);
        }
        __syncthreads();
        short8 af[4], bf[4];
#pragma unroll
        for (int i = 0; i < 4; ++i)
            af[i] = *(const short8*)&At[(mQuad + 16 * i + rsel) * 32 + ksel];
#pragma unroll
        for (int j = 0; j < 4; ++j)
            bf[j] = *(const short8*)&Bt[(nQuad + 16 * j + rsel) * 32 + ksel];
#pragma unroll
        for (int i = 0; i < 4; ++i)
#pragma unroll
            for (int j = 0; j < 4; ++j)
                acc[i][j] = __builtin_amdgcn_mfma_f32_16x16x32_bf16(bf[j], af[i], acc[i][j], 0, 0, 0);
        __syncthreads();
    }

    int rowq4 = (lane >> 4) * 4;     // n_local base of this lane's 4 cols
    float4 bias[4];
#pragma unroll
    for (int nt = 0; nt < 4; ++nt)
        bias[nt] = *(const float4*)(bcat + nBlk + nQuad + 16 * nt + rowq4);

    if (ysel == 0 || ysel == 2) {            // fp8 outputs (q / v)
        unsigned char* outp = (ysel == 0) ? q8 : v8;
#pragma unroll
        for (int mt = 0; mt < 4; ++mt) {
            int m = mBase + mQuad + 16 * mt + (lane & 15);
            if (m < n) {
                unsigned char* rowp = outp + (size_t)m * 256 + nQuad + rowq4;
#pragma unroll
                for (int nt = 0; nt < 4; ++nt) {
                    int pk = __builtin_amdgcn_cvt_pk_fp8_f32(
                        acc[mt][nt][0] + bias[nt].x, acc[mt][nt][1] + bias[nt].y, 0, false);
                    pk = __builtin_amdgcn_cvt_pk_fp8_f32(
                        acc[mt][nt][2] + bias[nt].z, acc[mt][nt][3] + bias[nt].w, pk, true);
                    *(int*)(rowp + 16 * nt) = pk;
                }
            }
        }
    } else {                                  // bf16 outputs (k / skip)
        ushort* outp = (ysel == 1) ? kb : sb;
#pragma unroll
        for (int mt = 0; mt < 4; ++mt) {
            int m = mBase + mQuad + 16 * mt + (lane & 15);
            if (m < n) {
                ushort* rowp = outp + (size_t)m * 256 + nQuad + rowq4;
#pragma unroll
                for (int nt = 0; nt < 4; ++nt) {
                    uint lo = (uint)f2bf(acc[mt][nt][0] + bias[nt].x)
                            | ((uint)f2bf(acc[mt][nt][1] + bias[nt].y) << 16);
                    uint hi = (uint)f2bf(acc[mt][nt][2] + bias[nt].z)
                            | ((uint)f2bf(acc[mt][nt][3] + bias[nt].w) << 16);
                    *(uint2*)(rowp + 16 * nt) = make_uint2(lo, hi);
                }
            }
        }
    }
}

// ---------------- per-node attention + epilogue ----------------
// One wave per dst node. Layout: lane owns 8 consecutive features
// f0 = (lane&31)*8; the two 32-lane halves process different edges
// (2 edges per iteration, unrolled x2 -> 4 edges / 8 gathers in flight).
// Logit reduce: 8 lanes per head -> 3 shfl_xor. Softmax without max
// subtraction (shift-invariant; logits tiny). Cross-half combine at end;
// epilogue runs redundantly in both halves (identical data), stores split.
__global__ __launch_bounds__(256) void node_kernel(
    const unsigned char* __restrict__ q8, const ushort* __restrict__ kb,
    const unsigned char* __restrict__ v8, const ushort* __restrict__ sbuf,
    const int* __restrict__ srclist, const int* __restrict__ start,
    const int* __restrict__ counts,
    const float* __restrict__ Wg, const float* __restrict__ bg,
    const float* __restrict__ lnw, const float* __restrict__ lnb,
    const float* __restrict__ pa,
    float* __restrict__ out, int n, int E)
{
    int wvi = threadIdx.x >> 6;
    int lane = threadIdx.x & 63;
    int node = blockIdx.x * 4 + wvi;
    if (node >= n) return;

    int l32 = lane & 31;
    int half = lane >> 5;
    int f0 = l32 * 8;                 // 8 consecutive features, all in head l32>>3

    short8 kv = *(const short8*)(kb + (size_t)node * 256 + f0);
    float kf[8];
#pragma unroll
    for (int i = 0; i < 8; ++i) kf[i] = bf2f((unsigned short)kv[i]);

    float acc[8];
#pragma unroll
    for (int i = 0; i < 8; ++i) acc[i] = 0.f;
    float denom = 0.f;

    int sidx = start[node], cnt = counts[node];

    for (int base = 0; base < cnt; base += 64) {
        int m = min(64, cnt - base);
        int batch = srclist[min(sidx + base + lane, E - 1)];
        for (int j = 0; j < m; j += 4) {
            int j0 = j + half;
            int j1 = j0 + 2;
            bool vld0 = j0 < m;        // half 0 always valid for j0
            bool vld1 = j1 < m;
            int s0 = __shfl(batch, vld0 ? j0 : j);
            int s1 = __shfl(batch, vld1 ? j1 : j);
            uint2 qw0 = *(const uint2*)(q8 + (size_t)s0 * 256 + f0);
            uint2 vw0 = *(const uint2*)(v8 + (size_t)s0 * 256 + f0);
            uint2 qw1 = *(const uint2*)(q8 + (size_t)s1 * 256 + f0);
            uint2 vw1 = *(const uint2*)(v8 + (size_t)s1 * 256 + f0);

            floatx2 qa0 = __builtin_amdgcn_cvt_pk_f32_fp8(qw0.x, false);
            floatx2 qa1 = __builtin_amdgcn_cvt_pk_f32_fp8(qw0.x, true);
            floatx2 qa2 = __builtin_amdgcn_cvt_pk_f32_fp8(qw0.y, false);
            floatx2 qa3 = __builtin_amdgcn_cvt_pk_f32_fp8(qw0.y, true);
            floatx2 qb0 = __builtin_amdgcn_cvt_pk_f32_fp8(qw1.x, false);
            floatx2 qb1 = __builtin_amdgcn_cvt_pk_f32_fp8(qw1.x, true);
            floatx2 qb2 = __builtin_amdgcn_cvt_pk_f32_fp8(qw1.y, false);
            floatx2 qb3 = __builtin_amdgcn_cvt_pk_f32_fp8(qw1.y, true);

            float p0 = qa0[0]*kf[0] + qa0[1]*kf[1] + qa1[0]*kf[2] + qa1[1]*kf[3]
                     + qa2[0]*kf[4] + qa2[1]*kf[5] + qa3[0]*kf[6] + qa3[1]*kf[7];
            float p1 = qb0[0]*kf[0] + qb0[1]*kf[1] + qb1[0]*kf[2] + qb1[1]*kf[3]
                     + qb2[0]*kf[4] + qb2[1]*kf[5] + qb3[0]*kf[6] + qb3[1]*kf[7];
            p0 += __shfl_xor(p0, 1);  p1 += __shfl_xor(p1, 1);
            p0 += __shfl_xor(p0, 2);  p1 += __shfl_xor(p1, 2);
            p0 += __shfl_xor(p0, 4);  p1 += __shfl_xor(p1, 4);
            float w0 = vld0 ? __expf(p0 * 0.125f) : 0.f;
            float w1 = vld1 ? __expf(p1 * 0.125f) : 0.f;

            floatx2 va0 = __builtin_amdgcn_cvt_pk_f32_fp8(vw0.x, false);
            floatx2 va1 = __builtin_amdgcn_cvt_pk_f32_fp8(vw0.x, true);
            floatx2 va2 = __builtin_amdgcn_cvt_pk_f32_fp8(vw0.y, false);
            floatx2 va3 = __builtin_amdgcn_cvt_pk_f32_fp8(vw0.y, true);
            floatx2 vb0 = __builtin_amdgcn_cvt_pk_f32_fp8(vw1.x, false);
            floatx2 vb1 = __builtin_amdgcn_cvt_pk_f32_fp8(vw1.x, true);
            floatx2 vb2 = __builtin_amdgcn_cvt_pk_f32_fp8(vw1.y, false);
            floatx2 vb3 = __builtin_amdgcn_cvt_pk_f32_fp8(vw1.y, true);

            denom += w0 + w1;
            acc[0] = fmaf(w0, va0[0], fmaf(w1, vb0[0], acc[0]));
            acc[1] = fmaf(w0, va0[1], fmaf(w1, vb0[1], acc[1]));
            acc[2] = fmaf(w0, va1[0], fmaf(w1, vb1[0], acc[2]));
            acc[3] = fmaf(w0, va1[1], fmaf(w1, vb1[1], acc[3]));
            acc[4] = fmaf(w0, va2[0], fmaf(w1, vb2[0], acc[4]));
            acc[5] = fmaf(w0, va2[1], fmaf(w1, vb2[1], acc[5]));
            acc[6] = fmaf(w0, va3[0], fmaf(w1, vb3[0], acc[6]));
            acc[7] = fmaf(w0, va3[1], fmaf(w1, vb3[1], acc[7]));
        }
    }

    // combine the two halves (after this both halves hold identical data)
#pragma unroll
    for (int i = 0; i < 8; ++i) acc[i] += __shfl_xor(acc[i], 32);
    denom += __shfl_xor(denom, 32);
    float inv = (denom > 0.f) ? 1.f / denom : 0.f;
    float r[8];
#pragma unroll
    for (int i = 0; i < 8; ++i) r[i] = acc[i] * inv;

    short8 sv = *(const short8*)(sbuf + (size_t)node * 256 + f0);
    float s[8];
#pragma unroll
    for (int i = 0; i < 8; ++i) s[i] = bf2f((unsigned short)sv[i]);

    // gate: z = Wg . [skip | rst | skip-rst] + bg, sigmoid
    float4 wa0 = *(const float4*)(Wg + f0);
    float4 wa1 = *(const float4*)(Wg + f0 + 4);
    float4 wb0 = *(const float4*)(Wg + 256 + f0);
    float4 wb1 = *(const float4*)(Wg + 256 + f0 + 4);
    float4 wc0 = *(const float4*)(Wg + 512 + f0);
    float4 wc1 = *(const float4*)(Wg + 512 + f0 + 4);
    float z = wa0.x*s[0] + wa0.y*s[1] + wa0.z*s[2] + wa0.w*s[3]
            + wa1.x*s[4] + wa1.y*s[5] + wa1.z*s[6] + wa1.w*s[7]
            + wb0.x*r[0] + wb0.y*r[1] + wb0.z*r[2] + wb0.w*r[3]
            + wb1.x*r[4] + wb1.y*r[5] + wb1.z*r[6] + wb1.w*r[7]
            + wc0.x*(s[0]-r[0]) + wc0.y*(s[1]-r[1]) + wc0.z*(s[2]-r[2]) + wc0.w*(s[3]-r[3])
            + wc1.x*(s[4]-r[4]) + wc1.y*(s[5]-r[5]) + wc1.z*(s[6]-r[6]) + wc1.w*(s[7]-r[7]);
#pragma unroll
    for (int d = 16; d >= 1; d >>= 1) z += __shfl_xor(z, d);   // per-half = full sum
    z += bg[0];
    float g = 1.f / (1.f + __expf(-z));

    float y[8];
#pragma unroll
    for (int i = 0; i < 8; ++i) y[i] = g * s[i] + (1.f - g) * r[i];

    float sum = y[0]+y[1]+y[2]+y[3]+y[4]+y[5]+y[6]+y[7];
#pragma unroll
    for (int d = 16; d >= 1; d >>= 1) sum += __shfl_xor(sum, d);
    float mu = sum * (1.f / 256.f);
    float dv[8];
    float sq = 0.f;
#pragma unroll
    for (int i = 0; i < 8; ++i) { dv[i] = y[i] - mu; sq = fmaf(dv[i], dv[i], sq); }
#pragma unroll
    for (int d = 16; d >= 1; d >>= 1) sq += __shfl_xor(sq, d);
    float rstd = rsqrtf(sq * (1.f / 256.f) + 1e-5f);

    float4 lw0 = *(const float4*)(lnw + f0);
    float4 lw1 = *(const float4*)(lnw + f0 + 4);
    float4 lb0 = *(const float4*)(lnb + f0);
    float4 lb1 = *(const float4*)(lnb + f0 + 4);
    float lwv[8] = {lw0.x, lw0.y, lw0.z, lw0.w, lw1.x, lw1.y, lw1.z, lw1.w};
    float lbv[8] = {lb0.x, lb0.y, lb0.z, lb0.w, lb1.x, lb1.y, lb1.z, lb1.w};
    float ap = pa[0];
    float o[8];
#pragma unroll
    for (int i = 0; i < 8; ++i) {
        float t = dv[i] * rstd * lwv[i] + lbv[i];
        o[i] = (t >= 0.f) ? t : ap * t;
    }

    // halves hold identical o[]; half 0 stores o[0..3], half 1 stores o[4..7]
    float4 stv;
    stv.x = half ? o[4] : o[0];
    stv.y = half ? o[5] : o[1];
    stv.z = half ? o[6] : o[2];
    stv.w = half ? o[7] : o[3];
    *(float4*)(out + (size_t)node * 256 + f0 + 4 * half) = stv;
}

// ---------------- launch ----------------

extern "C" void kernel_launch(void* const* d_in, const int* in_sizes, int n_in,
                              void* d_out, int out_size, void* d_ws, size_t ws_size,
                              hipStream_t stream)
{
    const float* feat = (const float*)d_in[0];
    const int* src    = (const int*)d_in[1];
    const int* dst    = (const int*)d_in[2];
    const float* Wq   = (const float*)d_in[3];
    const float* bq   = (const float*)d_in[4];
    const float* Wk   = (const float*)d_in[5];
    const float* bk   = (const float*)d_in[6];
    const float* Wv   = (const float*)d_in[7];
    const float* bv   = (const float*)d_in[8];
    const float* Wsk  = (const float*)d_in[9];
    const float* bsk  = (const float*)d_in[10];
    const float* Wg   = (const float*)d_in[11];
    const float* bg   = (const float*)d_in[12];
    const float* lnw  = (const float*)d_in[13];
    const float* lnb  = (const float*)d_in[14];
    const float* pa   = (const float*)d_in[15];

    int N = in_sizes[0] / 256;
    int E = in_sizes[1];
    float* out = (float*)d_out;

    int Mtiles = (N + 127) / 128;
    int Npad = Mtiles * 128;

    char* ws = (char*)d_ws;
    size_t off = 0;
    auto alloc = [&](size_t bytes) { char* p = ws + off; off = (off + bytes + 255) & ~(size_t)255; return p; };
    ushort* featb      = (ushort*)alloc((size_t)Npad * 256 * 2);
    ushort* Wcat       = (ushort*)alloc(1024 * 256 * 2);
    float*  bcat       = (float*) alloc(1024 * 4);
    unsigned char* q8  = (unsigned char*)alloc((size_t)N * 256);
    unsigned char* v8  = (unsigned char*)alloc((size_t)N * 256);
    ushort* kb         = (ushort*)alloc((size_t)N * 256 * 2);
    ushort* sb         = (ushort*)alloc((size_t)N * 256 * 2);
    int* counts        = (int*)alloc((size_t)N * 4);
    int* startv        = (int*)alloc((size_t)N * 4);
    int* cur           = (int*)alloc((size_t)N * 4);
    int* cursor        = (int*)alloc(4);
    int* srclist       = (int*)alloc((size_t)E * 4);

    int totPad = Npad * 256;
    int prepThreads = totPad / 4 + 65536 + 256 + N;
    prep_kernel<<<(prepThreads + 255) / 256, 256, 0, stream>>>(
        feat, featb, N * 256, totPad, Wq, Wk, Wv, Wsk, bq, bk, bv, bsk,
        Wcat, bcat, counts, cursor, N);

    count_kernel<<<(E + 255) / 256, 256, 0, stream>>>(dst, counts, E);
    alloc_kernel<<<(N + 255) / 256, 256, 0, stream>>>(counts, startv, cur, cursor, N);
    fill_kernel<<<(E + 255) / 256, 256, 0, stream>>>(dst, src, cur, srclist, E);

    dim3 gg(4, Mtiles);
    mfma_gemm<<<gg, 512, 0, stream>>>(featb, Wcat, bcat, q8, kb, v8, sb, N);

    node_kernel<<<(N + 3) / 4, 256, 0, stream>>>(q8, kb, v8, sb, srclist, startv, counts,
                                                 Wg, bg, lnw, lnb, pa, out, N, E);
}